// Round 4
// baseline (172.648 us; speedup 1.0000x reference)
//
#include <hip/hip_runtime.h>
#include <hip/hip_bf16.h>
#include <cstdint>
#include <cstddef>
#include <cmath>

#define NB 8
#define NL 1024
#define NT 1024
#define ND 768
#define NH 12
#define NDH 64
#define NM (NB*NL)

typedef short short8 __attribute__((ext_vector_type(8)));
typedef unsigned short ushort4v __attribute__((ext_vector_type(4)));
typedef unsigned int uint4v __attribute__((ext_vector_type(4)));
typedef float f32x4 __attribute__((ext_vector_type(4)));
typedef float float4v __attribute__((ext_vector_type(4)));

__device__ __forceinline__ unsigned short f2bf(float f) {
  union { __hip_bfloat16 h; unsigned short u; } cv;
  cv.h = __float2bfloat16(f);
  return cv.u;
}
__device__ __forceinline__ unsigned pk2(float lo, float hi) {
  return (unsigned)f2bf(lo) | ((unsigned)f2bf(hi) << 16);
}
__device__ __forceinline__ short8 cvt8(float4v x0, float4v x1) {
  union { short8 s; uint4v u; } r;
  r.u = (uint4v){pk2(x0[0], x0[1]), pk2(x0[2], x0[3]),
                 pk2(x1[0], x1[1]), pk2(x1[2], x1[3])};
  return r.s;
}
// async global->LDS, 16B per lane; LDS dest = wave-uniform base + lane*16
__device__ __forceinline__ void gll16(const void* g, void* l) {
  __builtin_amdgcn_global_load_lds(
      (const __attribute__((address_space(1))) unsigned int*)g,
      (__attribute__((address_space(3))) unsigned int*)l, 16, 0, 0);
}

// ---------------------------------------------------------------------------
// Weight convert+transpose: Wt[z][n][k] = bf16(W[z][k][n]), z in {q,k,v,o}
// ---------------------------------------------------------------------------
__global__ __launch_bounds__(256) void wt_kernel(
    const float* __restrict__ W0, const float* __restrict__ W1,
    const float* __restrict__ W2, const float* __restrict__ W3,
    unsigned short* __restrict__ Wt) {
  __shared__ float tile[32][33];
  const float* W = blockIdx.z == 0 ? W0 : blockIdx.z == 1 ? W1 : blockIdx.z == 2 ? W2 : W3;
  const int k0 = blockIdx.x * 32, n0 = blockIdx.y * 32;
  const int tx = threadIdx.x & 31, ty = threadIdx.x >> 5;
  for (int r = ty; r < 32; r += 8) tile[r][tx] = W[(size_t)(k0 + r) * ND + n0 + tx];
  __syncthreads();
  unsigned short* out = Wt + (size_t)blockIdx.z * ND * ND;
  for (int r = ty; r < 32; r += 8) out[(size_t)(n0 + r) * ND + k0 + tx] = f2bf(tile[tx][r]);
}

// ---------------------------------------------------------------------------
// GEMM 128x128 tile, BK=64, 4 waves, 4x4 16x16x32 frags, swizzled LDS.
// A staged via global_load_lds: fp32 directly for projections (convert to
// bf16 at fragment read, cvt_pk), bf16 for the out-projection.
// MODE 0: z=blockIdx.z in {0,1}: A = q/k fp32 -> qhb/khb bf16;
//         mfma(b,a) (swapped) -> j runs along cols -> ushort4 stores.
//         z==0 scaled by 0.125*log2e (softmax runs in exp2 domain).
// MODE 2: A = v fp32 -> vhT[(b*NH+h)*64+d][t] (transposed epilogue),
//         mfma(a,b) -> j runs along rows=t -> ushort4 along t.
// MODE 3: A = aob bf16 -> out fp32 + bias, mfma(b,a), float4 stores.
// LDS: bf16 rows 128B = 8 chunks, swizzle chunk^(row&7);
//      fp32 rows 256B = 16 chunks, swizzle chunk^(row&15). (chunk = 16B)
// ---------------------------------------------------------------------------
template<int MODE>
__global__ __launch_bounds__(256) void gemm_kernel(
    const float* __restrict__ Af0, const float* __restrict__ Af1,
    const unsigned short* __restrict__ Ab, const unsigned short* __restrict__ Wt,
    const float* __restrict__ bias0, const float* __restrict__ bias1,
    unsigned short* __restrict__ outb0, unsigned short* __restrict__ outb1,
    float* __restrict__ outf) {
  constexpr bool AF32 = (MODE != 3);
  __shared__ __align__(16) unsigned char AsRaw[AF32 ? 128 * 64 * 4 : 128 * 64 * 2];
  __shared__ __align__(16) unsigned short Bs[128 * 64];
  const int tid = threadIdx.x, lane = tid & 63, w = tid >> 6;
  const int c = lane & 15, g = lane >> 4;
  const int wrow = w & 1, wcol = w >> 1;
  const int l8 = lane >> 3, l7 = lane & 7, csw = l7 ^ l8;
  const int mbase = blockIdx.x * 128, nbase = blockIdx.y * 128;
  const int z = (MODE == 0) ? blockIdx.z : MODE;

  const float* Af = AF32 ? ((MODE == 0 && z == 1) ? Af1 : Af0) : nullptr;
  const unsigned short* Bt = Wt + (size_t)z * ND * ND;
  const float* bias = (MODE == 0 && z == 1) ? bias1 : bias0;

  f32x4 acc[4][4];
#pragma unroll
  for (int m = 0; m < 4; m++)
#pragma unroll
    for (int n = 0; n < 4; n++) acc[m][n] = (f32x4){0.f, 0.f, 0.f, 0.f};

  for (int k0 = 0; k0 < ND; k0 += 64) {
    if (AF32) {
      float* Asf = (float*)AsRaw;
      // 8 gll/wave: each covers 4 rows x 16 chunks (1KB); src pre-swizzled
#pragma unroll
      for (int it = 0; it < 8; it++) {
        int r0 = it * 16 + w * 4;
        int r = r0 + (lane >> 4);
        int gc = (lane & 15) ^ (r & 15);
        gll16(&Af[(size_t)(mbase + r) * ND + k0 + gc * 4], &Asf[r0 * 64]);
      }
    } else {
      unsigned short* Asb = (unsigned short*)AsRaw;
#pragma unroll
      for (int it = 0; it < 4; it++) {
        int r = it * 32 + w * 8 + l8;
        gll16(&Ab[(size_t)(mbase + r) * ND + k0 + csw * 8], &Asb[(it * 32 + w * 8) * 64]);
      }
    }
#pragma unroll
    for (int it = 0; it < 4; it++) {
      int r = it * 32 + w * 8 + l8;
      gll16(&Bt[(size_t)(nbase + r) * ND + k0 + csw * 8], &Bs[(it * 32 + w * 8) * 64]);
    }
    __syncthreads();

#pragma unroll
    for (int ks = 0; ks < 2; ks++) {
      short8 a[4], b[4];
#pragma unroll
      for (int m = 0; m < 4; m++) {
        int r = wrow * 64 + m * 16 + c;
        if (AF32) {
          const float* Asf = (const float*)AsRaw;
          int cc = ks * 8 + g * 2;
          float4v x0 = *(const float4v*)&Asf[r * 64 + ((cc ^ (r & 15)) * 4)];
          float4v x1 = *(const float4v*)&Asf[r * 64 + (((cc + 1) ^ (r & 15)) * 4)];
          a[m] = cvt8(x0, x1);
        } else {
          const unsigned short* Asb = (const unsigned short*)AsRaw;
          a[m] = *(const short8*)&Asb[r * 64 + (((ks * 4 + g) ^ (c & 7)) * 8)];
        }
      }
#pragma unroll
      for (int n = 0; n < 4; n++) {
        int r = wcol * 64 + n * 16 + c;
        b[n] = *(const short8*)&Bs[r * 64 + (((ks * 4 + g) ^ (c & 7)) * 8)];
      }
#pragma unroll
      for (int m = 0; m < 4; m++)
#pragma unroll
        for (int n = 0; n < 4; n++) {
          if (MODE == 2)
            acc[m][n] = __builtin_amdgcn_mfma_f32_16x16x32_bf16(a[m], b[n], acc[m][n], 0, 0, 0);
          else
            acc[m][n] = __builtin_amdgcn_mfma_f32_16x16x32_bf16(b[n], a[m], acc[m][n], 0, 0, 0);
        }
    }
    __syncthreads();
  }

  // ---- epilogues
  if (MODE == 2) {
    // lane holds C[r0+j][col], col = head-dim; write vhT[d][t] vectorized on t
#pragma unroll
    for (int n = 0; n < 4; n++) {
      const int col = nbase + wcol * 64 + n * 16 + c;
      const float bv = bias[col];
      const int h = col >> 6, dd = col & 63;
#pragma unroll
      for (int m = 0; m < 4; m++) {
        const int r0 = mbase + wrow * 64 + m * 16 + g * 4;
        const int bb = r0 >> 10, t = r0 & (NT - 1);
        ushort4v y;
#pragma unroll
        for (int j = 0; j < 4; j++) y[j] = f2bf(acc[m][n][j] + bv);
        *(ushort4v*)&outb0[((size_t)(bb * NH + h) * NDH + dd) * NT + t] = y;
      }
    }
  } else {
    // swapped: lane holds C[row + c][colb + j]
    const float scale = (MODE == 0 && z == 0) ? 0.125f * 1.44269504f : 1.0f;
    unsigned short* outb = (MODE == 0) ? (z == 0 ? outb0 : outb1) : nullptr;
#pragma unroll
    for (int n = 0; n < 4; n++) {
      const int colb = nbase + wcol * 64 + n * 16 + g * 4;
      float4v bv4 = *(const float4v*)&bias[colb];
#pragma unroll
      for (int m = 0; m < 4; m++) {
        const int row = mbase + wrow * 64 + m * 16 + c;
        if (MODE == 3) {
          float4v y;
#pragma unroll
          for (int j = 0; j < 4; j++) y[j] = acc[m][n][j] + bv4[j];
          *(float4v*)&outf[(size_t)row * ND + colb] = y;
        } else {
          ushort4v y;
#pragma unroll
          for (int j = 0; j < 4; j++) y[j] = f2bf((acc[m][n][j] + bv4[j]) * scale);
          *(ushort4v*)&outb[(size_t)row * ND + colb] = y;
        }
      }
    }
  }
}

// ---------------------------------------------------------------------------
// Flash attention, swapped-QK^T form, exp2 domain (log2e folded into qh).
// 4 waves x 32 q-rows = 128 q/block. S^T = mfma(K, Q); softmax in-register;
// V pre-transposed (vhT) so PV = mfma(Vt, P^T). K/V double-buffered via
// global_load_lds, pre-swizzled source. T13 defer-max, mask-skip, T5 setprio.
// ---------------------------------------------------------------------------
__global__ __launch_bounds__(256) void attn_kernel(
    const unsigned short* __restrict__ qh, const unsigned short* __restrict__ kh,
    const unsigned short* __restrict__ vhT, const unsigned int* __restrict__ mask,
    unsigned short* __restrict__ ao) {
  __shared__ __align__(16) unsigned short Ks[2][64 * 64];
  __shared__ __align__(16) unsigned short Vs[2][64 * 64];
  __shared__ __align__(16) unsigned short Ps[4][32][72];
  const int tid = threadIdx.x, lane = tid & 63, w = tid >> 6;
  const int c = lane & 15, g = lane >> 4;
  const int l8 = lane >> 3, l7 = lane & 7, csw = l7 ^ l8;
  const int qb = blockIdx.x * 128;
  const int b = blockIdx.y / NH, h = blockIdx.y % NH;
  const size_t kbase = (size_t)b * NT * ND + h * NDH;
  const size_t vbase = (size_t)(b * NH + h) * NDH * NT;

  short8 aq[2][2];
#pragma unroll
  for (int half = 0; half < 2; half++) {
    size_t qrow = (size_t)(b * NL + qb + w * 32 + half * 16 + c) * ND + h * NDH;
#pragma unroll
    for (int ks = 0; ks < 2; ks++)
      aq[half][ks] = *(const short8*)&qh[qrow + ks * 32 + g * 8];
  }

  f32x4 o[2][4];
#pragma unroll
  for (int half = 0; half < 2; half++)
#pragma unroll
    for (int f = 0; f < 4; f++) o[half][f] = (f32x4){0.f, 0.f, 0.f, 0.f};
  float mr[2] = {-1e30f, -1e30f}, lr[2] = {0.f, 0.f};

#pragma unroll
  for (int it = 0; it < 2; it++) {
    int r = w * 16 + it * 8 + l8;
    gll16(&kh[kbase + (size_t)r * ND + csw * 8], &Ks[0][(w * 16 + it * 8) * 64]);
    gll16(&vhT[vbase + (size_t)r * NT + csw * 8], &Vs[0][(w * 16 + it * 8) * 64]);
  }
  __syncthreads();

  for (int t0 = 0; t0 < NT; t0 += 64) {
    const int cur = (t0 >> 6) & 1;
    if (t0 + 64 < NT) {
#pragma unroll
      for (int it = 0; it < 2; it++) {
        int r = w * 16 + it * 8 + l8;
        gll16(&kh[kbase + (size_t)(t0 + 64 + r) * ND + csw * 8],
              &Ks[cur ^ 1][(w * 16 + it * 8) * 64]);
        gll16(&vhT[vbase + (size_t)r * NT + (t0 + 64) + csw * 8],
              &Vs[cur ^ 1][(w * 16 + it * 8) * 64]);
      }
    }

    // ---- S^T = K Q (exp2 domain)
    f32x4 s[2][4];
#pragma unroll
    for (int half = 0; half < 2; half++)
#pragma unroll
      for (int n = 0; n < 4; n++) s[half][n] = (f32x4){0.f, 0.f, 0.f, 0.f};
    __builtin_amdgcn_s_setprio(1);
#pragma unroll
    for (int ks = 0; ks < 2; ks++)
#pragma unroll
      for (int n = 0; n < 4; n++) {
        short8 ak = *(const short8*)&Ks[cur][(n * 16 + c) * 64 + (((ks * 4 + g) ^ (c & 7)) * 8)];
        s[0][n] = __builtin_amdgcn_mfma_f32_16x16x32_bf16(ak, aq[0][ks], s[0][n], 0, 0, 0);
        s[1][n] = __builtin_amdgcn_mfma_f32_16x16x32_bf16(ak, aq[1][ks], s[1][n], 0, 0, 0);
      }
    __builtin_amdgcn_s_setprio(0);

    // ---- mask (skip when tile has no padding)
    {
      uint4v mm[4];
      unsigned any = 0;
#pragma unroll
      for (int n = 0; n < 4; n++) {
        mm[n] = *(const uint4v*)&mask[(size_t)b * NT + t0 + n * 16 + g * 4];
        any |= mm[n][0] | mm[n][1] | mm[n][2] | mm[n][3];
      }
      if (__any(any != 0u)) {
#pragma unroll
        for (int n = 0; n < 4; n++)
#pragma unroll
          for (int j = 0; j < 4; j++)
            if (mm[n][j]) { s[0][n][j] = -INFINITY; s[1][n][j] = -INFINITY; }
      }
    }

    // ---- online softmax with defer-max (T13), exp2 domain
#pragma unroll
    for (int half = 0; half < 2; half++) {
      float m01 = fmaxf(fmaxf(s[half][0][0], s[half][0][1]), fmaxf(s[half][0][2], s[half][0][3]));
      float m23 = fmaxf(fmaxf(s[half][1][0], s[half][1][1]), fmaxf(s[half][1][2], s[half][1][3]));
      float m45 = fmaxf(fmaxf(s[half][2][0], s[half][2][1]), fmaxf(s[half][2][2], s[half][2][3]));
      float m67 = fmaxf(fmaxf(s[half][3][0], s[half][3][1]), fmaxf(s[half][3][2], s[half][3][3]));
      float mt = fmaxf(fmaxf(m01, m23), fmaxf(m45, m67));
      mt = fmaxf(mt, __shfl_xor(mt, 16, 64));
      mt = fmaxf(mt, __shfl_xor(mt, 32, 64));
      if (!__all(mt <= mr[half] + 8.f)) {
        float mnew = fmaxf(mr[half], mt);
        float alpha = exp2f(mr[half] - mnew);
        lr[half] *= alpha;
#pragma unroll
        for (int f = 0; f < 4; f++)
#pragma unroll
          for (int j = 0; j < 4; j++) o[half][f][j] *= alpha;
        mr[half] = mnew;
      }
      float rs = 0.f;
#pragma unroll
      for (int n = 0; n < 4; n++)
#pragma unroll
        for (int j = 0; j < 4; j++) {
          float p = exp2f(s[half][n][j] - mr[half]);
          s[half][n][j] = p;
          rs += p;
        }
      rs += __shfl_xor(rs, 16, 64);
      rs += __shfl_xor(rs, 32, 64);
      lr[half] += rs;
      unsigned* pr = (unsigned*)&Ps[w][half * 16 + c][0];
#pragma unroll
      for (int n = 0; n < 4; n++) {
        pr[n * 8 + g * 2]     = pk2(s[half][n][0], s[half][n][1]);
        pr[n * 8 + g * 2 + 1] = pk2(s[half][n][2], s[half][n][3]);
      }
    }

    // ---- O^T += Vt P^T (wave-private Ps; no barrier)
    __builtin_amdgcn_s_setprio(1);
#pragma unroll
    for (int ks = 0; ks < 2; ks++) {
      short8 bp0 = *(const short8*)&Ps[w][c][ks * 32 + g * 8];
      short8 bp1 = *(const short8*)&Ps[w][16 + c][ks * 32 + g * 8];
#pragma unroll
      for (int f = 0; f < 4; f++) {
        short8 av = *(const short8*)&Vs[cur][(f * 16 + c) * 64 + (((ks * 4 + g) ^ (c & 7)) * 8)];
        o[0][f] = __builtin_amdgcn_mfma_f32_16x16x32_bf16(av, bp0, o[0][f], 0, 0, 0);
        o[1][f] = __builtin_amdgcn_mfma_f32_16x16x32_bf16(av, bp1, o[1][f], 0, 0, 0);
      }
    }
    __builtin_amdgcn_s_setprio(0);
    __syncthreads();
  }

#pragma unroll
  for (int half = 0; half < 2; half++) {
    float inv = 1.f / lr[half];
    size_t row = (size_t)(b * NL + qb + w * 32 + half * 16 + c) * ND + h * NDH;
#pragma unroll
    for (int f = 0; f < 4; f++) {
      ushort4v y;
#pragma unroll
      for (int j = 0; j < 4; j++) y[j] = f2bf(o[half][f][j] * inv);
      *(ushort4v*)&ao[row + f * 16 + g * 4] = y;
    }
  }
}

// ---------------------------------------------------------------------------
extern "C" void kernel_launch(void* const* d_in, const int* in_sizes, int n_in,
                              void* d_out, int out_size, void* d_ws, size_t ws_size,
                              hipStream_t stream) {
  const float* q  = (const float*)d_in[0];
  const float* k  = (const float*)d_in[1];
  const float* v  = (const float*)d_in[2];
  // d_in[3] = pairwise_locs: unused in the reference forward path
  const unsigned int* mask = (const unsigned int*)d_in[4];
  const float* Wq = (const float*)d_in[5];
  const float* bq = (const float*)d_in[6];
  const float* Wk = (const float*)d_in[7];
  const float* bk = (const float*)d_in[8];
  const float* Wv = (const float*)d_in[9];
  const float* bv = (const float*)d_in[10];
  const float* Wo = (const float*)d_in[11];
  const float* bo = (const float*)d_in[12];
  float* out = (float*)d_out;

  unsigned short* ws  = (unsigned short*)d_ws;
  unsigned short* Wt  = ws;                          // 4 * 768*768
  unsigned short* qhb = Wt + (size_t)4 * ND * ND;
  unsigned short* khb = qhb + (size_t)NM * ND;
  unsigned short* vhT = khb + (size_t)NM * ND;       // [(b*NH+h)*64+d][1024]
  unsigned short* aob = vhT + (size_t)NM * ND;

  wt_kernel<<<dim3(ND / 32, ND / 32, 4), 256, 0, stream>>>(Wq, Wk, Wv, Wo, Wt);

  // Q and K projections (fp32 A staged direct, convert at fragment read)
  gemm_kernel<0><<<dim3(NM / 128, ND / 128, 2), 256, 0, stream>>>(
      q, k, nullptr, Wt, bq, bk, qhb, khb, nullptr);
  // V projection -> transposed vhT
  gemm_kernel<2><<<dim3(NM / 128, ND / 128), 256, 0, stream>>>(
      v, nullptr, nullptr, Wt, bv, nullptr, vhT, nullptr, nullptr);

  attn_kernel<<<dim3(NL / 128, NB * NH), 256, 0, stream>>>(qhb, khb, vhT, mask, aob);

  gemm_kernel<3><<<dim3(NM / 128, ND / 128), 256, 0, stream>>>(
      nullptr, nullptr, aob, Wt, bo, nullptr, nullptr, nullptr, out);
}

// Round 6
// 168.547 us; speedup vs baseline: 1.0243x; 1.0243x over previous
//
#include <hip/hip_runtime.h>
#include <hip/hip_bf16.h>
#include <cstdint>
#include <cstddef>
#include <cmath>

#define NB 8
#define NL 1024
#define NT 1024
#define ND 768
#define NH 12
#define NDH 64
#define NM (NB*NL)

typedef short short8 __attribute__((ext_vector_type(8)));
typedef unsigned short ushort4v __attribute__((ext_vector_type(4)));
typedef unsigned int uint4v __attribute__((ext_vector_type(4)));
typedef unsigned int uint2v __attribute__((ext_vector_type(2)));
typedef float f32x4 __attribute__((ext_vector_type(4)));
typedef float float4v __attribute__((ext_vector_type(4)));

__device__ __forceinline__ unsigned short f2bf(float f) {
  union { __hip_bfloat16 h; unsigned short u; } cv;
  cv.h = __float2bfloat16(f);
  return cv.u;
}
__device__ __forceinline__ unsigned pk2(float lo, float hi) {
  return (unsigned)f2bf(lo) | ((unsigned)f2bf(hi) << 16);
}
__device__ __forceinline__ f32x4 vmax4(f32x4 a, f32x4 b) {
  f32x4 r;
  r[0] = fmaxf(a[0], b[0]); r[1] = fmaxf(a[1], b[1]);
  r[2] = fmaxf(a[2], b[2]); r[3] = fmaxf(a[3], b[3]);
  return r;
}
// async global->LDS, 16B per lane; LDS dest = wave-uniform base + lane*16
__device__ __forceinline__ void gll16(const void* g, void* l) {
  __builtin_amdgcn_global_load_lds(
      (const __attribute__((address_space(1))) unsigned int*)g,
      (__attribute__((address_space(3))) unsigned int*)l, 16, 0, 0);
}

// ---------------------------------------------------------------------------
// Weight convert+transpose: Wt[z][n][k] = bf16(W[z][k][n]), z in {q,k,v,o}
// ---------------------------------------------------------------------------
__global__ __launch_bounds__(256) void wt_kernel(
    const float* __restrict__ W0, const float* __restrict__ W1,
    const float* __restrict__ W2, const float* __restrict__ W3,
    unsigned short* __restrict__ Wt) {
  __shared__ float tile[32][33];
  const float* W = blockIdx.z == 0 ? W0 : blockIdx.z == 1 ? W1 : blockIdx.z == 2 ? W2 : W3;
  const int k0 = blockIdx.x * 32, n0 = blockIdx.y * 32;
  const int tx = threadIdx.x & 31, ty = threadIdx.x >> 5;
  for (int r = ty; r < 32; r += 8) tile[r][tx] = W[(size_t)(k0 + r) * ND + n0 + tx];
  __syncthreads();
  unsigned short* out = Wt + (size_t)blockIdx.z * ND * ND;
  for (int r = ty; r < 32; r += 8) out[(size_t)(n0 + r) * ND + k0 + tx] = f2bf(tile[tx][r]);
}

// ---------------------------------------------------------------------------
// GEMM 128x128 tile, BK=64, 4 waves, 4x4 16x16x32 frags, swizzled LDS.
// A staging: MODE!=3 -> fp32 global loads, convert to bf16 in registers,
// swizzled ds_write_b128 (round-2 form). MODE==3 -> bf16 via global_load_lds.
// B always via global_load_lds (pre-swizzled source).
// MODE 0: z=blockIdx.z in {0,1}: q/k proj -> bf16 qhb/khb; mfma(b,a) swapped
//         -> j runs along cols -> ushort4 stores. z0 scale 0.125*log2e.
// MODE 2: V proj -> vhT[(b*NH+h)*64+d][t] transposed epilogue; mfma(a,b).
// MODE 3: out-proj -> fp32 out + bias, mfma(b,a), float4 stores.
// LDS: bf16 rows 128B = 8 chunks of 16B, swizzle chunk^(row&7).
// ---------------------------------------------------------------------------
template<int MODE>
__global__ __launch_bounds__(256) void gemm_kernel(
    const float* __restrict__ Af0, const float* __restrict__ Af1,
    const unsigned short* __restrict__ Ab, const unsigned short* __restrict__ Wt,
    const float* __restrict__ bias0, const float* __restrict__ bias1,
    unsigned short* __restrict__ outb0, unsigned short* __restrict__ outb1,
    float* __restrict__ outf) {
  __shared__ __align__(16) unsigned short As[128 * 64];
  __shared__ __align__(16) unsigned short Bs[128 * 64];
  const int tid = threadIdx.x, lane = tid & 63, w = tid >> 6;
  const int c = lane & 15, g = lane >> 4;
  const int wrow = w & 1, wcol = w >> 1;
  const int l8 = lane >> 3, l7 = lane & 7, csw = l7 ^ l8;
  const int mbase = blockIdx.x * 128, nbase = blockIdx.y * 128;
  const int z = (MODE == 0) ? blockIdx.z : MODE;

  const float* Af = (MODE == 0) ? (z == 0 ? Af0 : Af1) : Af0;
  const unsigned short* Bt = Wt + (size_t)z * ND * ND;
  const float* bias = (MODE == 0 && z == 1) ? bias1 : bias0;

  f32x4 acc[4][4];
#pragma unroll
  for (int m = 0; m < 4; m++)
#pragma unroll
    for (int n = 0; n < 4; n++) acc[m][n] = (f32x4){0.f, 0.f, 0.f, 0.f};

  for (int k0 = 0; k0 < ND; k0 += 64) {
    if (MODE != 3) {
      // reg-stage fp32 -> bf16, 4 chunks (16B) per thread, swizzled write
#pragma unroll
      for (int i = 0; i < 4; i++) {
        int id = i * 256 + tid;          // chunk id 0..1023 (128 rows x 8)
        int r = id >> 3, cc = id & 7;
        const float* src = &Af[(size_t)(mbase + r) * ND + k0 + cc * 8];
        float4v x0 = *(const float4v*)src;
        float4v x1 = *(const float4v*)(src + 4);
        uint4v y = {pk2(x0[0], x0[1]), pk2(x0[2], x0[3]),
                    pk2(x1[0], x1[1]), pk2(x1[2], x1[3])};
        *(uint4v*)&As[r * 64 + ((cc ^ (r & 7)) * 8)] = y;
      }
    } else {
#pragma unroll
      for (int it = 0; it < 4; it++) {
        int r = it * 32 + w * 8 + l8;
        gll16(&Ab[(size_t)(mbase + r) * ND + k0 + csw * 8], &As[(it * 32 + w * 8) * 64]);
      }
    }
#pragma unroll
    for (int it = 0; it < 4; it++) {
      int r = it * 32 + w * 8 + l8;
      gll16(&Bt[(size_t)(nbase + r) * ND + k0 + csw * 8], &Bs[(it * 32 + w * 8) * 64]);
    }
    __syncthreads();

#pragma unroll
    for (int ks = 0; ks < 2; ks++) {
      short8 a[4], b[4];
#pragma unroll
      for (int m = 0; m < 4; m++) {
        int r = wrow * 64 + m * 16 + c;
        a[m] = *(const short8*)&As[r * 64 + (((ks * 4 + g) ^ (c & 7)) * 8)];
      }
#pragma unroll
      for (int n = 0; n < 4; n++) {
        int r = wcol * 64 + n * 16 + c;
        b[n] = *(const short8*)&Bs[r * 64 + (((ks * 4 + g) ^ (c & 7)) * 8)];
      }
#pragma unroll
      for (int m = 0; m < 4; m++)
#pragma unroll
        for (int n = 0; n < 4; n++) {
          if (MODE == 2)
            acc[m][n] = __builtin_amdgcn_mfma_f32_16x16x32_bf16(a[m], b[n], acc[m][n], 0, 0, 0);
          else
            acc[m][n] = __builtin_amdgcn_mfma_f32_16x16x32_bf16(b[n], a[m], acc[m][n], 0, 0, 0);
        }
    }
    __syncthreads();
  }

  // ---- epilogues
  if (MODE == 2) {
    // lane holds C[r0+j][col], col = head-dim; write vhT[d][t] vectorized on t
#pragma unroll
    for (int n = 0; n < 4; n++) {
      const int col = nbase + wcol * 64 + n * 16 + c;
      const float bv = bias[col];
      const int h = col >> 6, dd = col & 63;
#pragma unroll
      for (int m = 0; m < 4; m++) {
        const int r0 = mbase + wrow * 64 + m * 16 + g * 4;
        const int bb = r0 >> 10, t = r0 & (NT - 1);
        ushort4v y;
#pragma unroll
        for (int j = 0; j < 4; j++) y[j] = f2bf(acc[m][n][j] + bv);
        *(ushort4v*)&outb0[((size_t)(bb * NH + h) * NDH + dd) * NT + t] = y;
      }
    }
  } else {
    // swapped: lane holds C[row + c][colb + j]
    const float scale = (MODE == 0 && z == 0) ? 0.125f * 1.44269504f : 1.0f;
    unsigned short* outb = (MODE == 0) ? (z == 0 ? outb0 : outb1) : nullptr;
#pragma unroll
    for (int n = 0; n < 4; n++) {
      const int colb = nbase + wcol * 64 + n * 16 + g * 4;
      float4v bv4 = *(const float4v*)&bias[colb];
#pragma unroll
      for (int m = 0; m < 4; m++) {
        const int row = mbase + wrow * 64 + m * 16 + c;
        if (MODE == 3) {
          float4v y;
#pragma unroll
          for (int j = 0; j < 4; j++) y[j] = acc[m][n][j] + bv4[j];
          *(float4v*)&outf[(size_t)row * ND + colb] = y;
        } else {
          ushort4v y;
#pragma unroll
          for (int j = 0; j < 4; j++) y[j] = f2bf((acc[m][n][j] + bv4[j]) * scale);
          *(ushort4v*)&outb[(size_t)row * ND + colb] = y;
        }
      }
    }
  }
}

// ---------------------------------------------------------------------------
// Flash attention, swapped-QK^T, exp2 domain. 4 waves x 32 q = 128 q/block.
// Softmax per-tile: NO cross-lane ops in steady state — per-lane partial
// sums in f32x4 (reduced once in epilogue), lane-local defer-max with a
// single wave-uniform __all() check (rescale path w/ shfl only on trigger).
// Mask via one __ballot per tile; fully-masked tiles skip compute.
// ---------------------------------------------------------------------------
__global__ __launch_bounds__(256) void attn_kernel(
    const unsigned short* __restrict__ qh, const unsigned short* __restrict__ kh,
    const unsigned short* __restrict__ vhT, const unsigned int* __restrict__ mask,
    unsigned short* __restrict__ ao) {
  __shared__ __align__(16) unsigned short Ks[2][64 * 64];
  __shared__ __align__(16) unsigned short Vs[2][64 * 64];
  __shared__ __align__(16) unsigned short Ps[4][32][72];
  const int tid = threadIdx.x, lane = tid & 63, w = tid >> 6;
  const int c = lane & 15, g = lane >> 4;
  const int l8 = lane >> 3, l7 = lane & 7, csw = l7 ^ l8;
  const int qb = blockIdx.x * 128;
  const int b = blockIdx.y / NH, h = blockIdx.y % NH;
  const size_t kbase = (size_t)b * NT * ND + h * NDH;
  const size_t vbase = (size_t)(b * NH + h) * NDH * NT;

  short8 aq[2][2];
#pragma unroll
  for (int half = 0; half < 2; half++) {
    size_t qrow = (size_t)(b * NL + qb + w * 32 + half * 16 + c) * ND + h * NDH;
#pragma unroll
    for (int ks = 0; ks < 2; ks++)
      aq[half][ks] = *(const short8*)&qh[qrow + ks * 32 + g * 8];
  }

  f32x4 o[2][4], lrv[2];
#pragma unroll
  for (int half = 0; half < 2; half++) {
    lrv[half] = (f32x4){0.f, 0.f, 0.f, 0.f};
#pragma unroll
    for (int f = 0; f < 4; f++) o[half][f] = (f32x4){0.f, 0.f, 0.f, 0.f};
  }
  float mr[2] = {-1e30f, -1e30f};

#pragma unroll
  for (int it = 0; it < 2; it++) {
    int r = w * 16 + it * 8 + l8;
    gll16(&kh[kbase + (size_t)r * ND + csw * 8], &Ks[0][(w * 16 + it * 8) * 64]);
    gll16(&vhT[vbase + (size_t)r * NT + csw * 8], &Vs[0][(w * 16 + it * 8) * 64]);
  }
  __syncthreads();

  for (int t0 = 0; t0 < NT; t0 += 64) {
    const int cur = (t0 >> 6) & 1;
    if (t0 + 64 < NT) {
#pragma unroll
      for (int it = 0; it < 2; it++) {
        int r = w * 16 + it * 8 + l8;
        gll16(&kh[kbase + (size_t)(t0 + 64 + r) * ND + csw * 8],
              &Ks[cur ^ 1][(w * 16 + it * 8) * 64]);
        gll16(&vhT[vbase + (size_t)r * NT + (t0 + 64) + csw * 8],
              &Vs[cur ^ 1][(w * 16 + it * 8) * 64]);
      }
    }

    // one mask word per lane -> wave-uniform 64-bit tile mask
    unsigned long long tm = __ballot(mask[(size_t)b * NT + t0 + lane] != 0u);

    if (tm != ~0ull) {  // skip fully-padded tiles
      // ---- S^T = K Q (exp2 domain)
      f32x4 s[2][4];
#pragma unroll
      for (int half = 0; half < 2; half++)
#pragma unroll
        for (int n = 0; n < 4; n++) s[half][n] = (f32x4){0.f, 0.f, 0.f, 0.f};
      __builtin_amdgcn_s_setprio(1);
#pragma unroll
      for (int ks = 0; ks < 2; ks++)
#pragma unroll
        for (int n = 0; n < 4; n++) {
          short8 ak = *(const short8*)&Ks[cur][(n * 16 + c) * 64 + (((ks * 4 + g) ^ (c & 7)) * 8)];
          s[0][n] = __builtin_amdgcn_mfma_f32_16x16x32_bf16(ak, aq[0][ks], s[0][n], 0, 0, 0);
          s[1][n] = __builtin_amdgcn_mfma_f32_16x16x32_bf16(ak, aq[1][ks], s[1][n], 0, 0, 0);
        }
      __builtin_amdgcn_s_setprio(0);

      if (tm) {  // partial padding: lane's bits are at (n*16 + j) of tm>>(g*4)
        unsigned long long tms = tm >> (g * 4);
#pragma unroll
        for (int n = 0; n < 4; n++)
#pragma unroll
          for (int j = 0; j < 4; j++)
            if ((tms >> (n * 16 + j)) & 1) { s[0][n][j] = -INFINITY; s[1][n][j] = -INFINITY; }
      }

      // ---- lane-local max + deferred rescale check
      float mt[2];
#pragma unroll
      for (int half = 0; half < 2; half++) {
        f32x4 mv = vmax4(vmax4(s[half][0], s[half][1]), vmax4(s[half][2], s[half][3]));
        mt[half] = fmaxf(fmaxf(mv[0], mv[1]), fmaxf(mv[2], mv[3]));
      }
      bool ok = (mt[0] <= mr[0] + 8.f) && (mt[1] <= mr[1] + 8.f);
      if (!__all(ok)) {  // rare: true row max + rescale (wave-uniform branch)
#pragma unroll
        for (int half = 0; half < 2; half++) {
          float mrow = mt[half];
          mrow = fmaxf(mrow, __shfl_xor(mrow, 16, 64));
          mrow = fmaxf(mrow, __shfl_xor(mrow, 32, 64));
          float mnew = fmaxf(mr[half], mrow);
          float alpha = exp2f(mr[half] - mnew);
          mr[half] = mnew;
#pragma unroll
          for (int j = 0; j < 4; j++) lrv[half][j] *= alpha;
#pragma unroll
          for (int f = 0; f < 4; f++)
#pragma unroll
            for (int j = 0; j < 4; j++) o[half][f][j] *= alpha;
        }
      }

      // ---- P = exp2(S - m), per-lane partial sums, pack to LDS (b64)
#pragma unroll
      for (int half = 0; half < 2; half++) {
#pragma unroll
        for (int n = 0; n < 4; n++) {
#pragma unroll
          for (int j = 0; j < 4; j++) s[half][n][j] = exp2f(s[half][n][j] - mr[half]);
          lrv[half] += s[half][n];
        }
        unsigned* pr = (unsigned*)&Ps[w][half * 16 + c][0];
#pragma unroll
        for (int n = 0; n < 4; n++) {
          uint2v y = {pk2(s[half][n][0], s[half][n][1]), pk2(s[half][n][2], s[half][n][3])};
          *(uint2v*)&pr[n * 8 + g * 2] = y;
        }
      }

      // ---- O^T += Vt P^T (wave-private Ps; no barrier)
      __builtin_amdgcn_s_setprio(1);
#pragma unroll
      for (int ks = 0; ks < 2; ks++) {
        short8 bp0 = *(const short8*)&Ps[w][c][ks * 32 + g * 8];
        short8 bp1 = *(const short8*)&Ps[w][16 + c][ks * 32 + g * 8];
#pragma unroll
        for (int f = 0; f < 4; f++) {
          short8 av = *(const short8*)&Vs[cur][(f * 16 + c) * 64 + (((ks * 4 + g) ^ (c & 7)) * 8)];
          o[0][f] = __builtin_amdgcn_mfma_f32_16x16x32_bf16(av, bp0, o[0][f], 0, 0, 0);
          o[1][f] = __builtin_amdgcn_mfma_f32_16x16x32_bf16(av, bp1, o[1][f], 0, 0, 0);
        }
      }
      __builtin_amdgcn_s_setprio(0);
    }
    __syncthreads();
  }

  // ---- epilogue: reduce l across lane groups once, scale, store
#pragma unroll
  for (int half = 0; half < 2; half++) {
    float lr = (lrv[half][0] + lrv[half][1]) + (lrv[half][2] + lrv[half][3]);
    lr += __shfl_xor(lr, 16, 64);
    lr += __shfl_xor(lr, 32, 64);
    float inv = 1.f / lr;
    size_t row = (size_t)(b * NL + qb + w * 32 + half * 16 + c) * ND + h * NDH;
#pragma unroll
    for (int f = 0; f < 4; f++) {
      ushort4v y;
#pragma unroll
      for (int j = 0; j < 4; j++) y[j] = f2bf(o[half][f][j] * inv);
      *(ushort4v*)&ao[row + f * 16 + g * 4] = y;
    }
  }
}

// ---------------------------------------------------------------------------
extern "C" void kernel_launch(void* const* d_in, const int* in_sizes, int n_in,
                              void* d_out, int out_size, void* d_ws, size_t ws_size,
                              hipStream_t stream) {
  const float* q  = (const float*)d_in[0];
  const float* k  = (const float*)d_in[1];
  const float* v  = (const float*)d_in[2];
  // d_in[3] = pairwise_locs: unused in the reference forward path
  const unsigned int* mask = (const unsigned int*)d_in[4];
  const float* Wq = (const float*)d_in[5];
  const float* bq = (const float*)d_in[6];
  const float* Wk = (const float*)d_in[7];
  const float* bk = (const float*)d_in[8];
  const float* Wv = (const float*)d_in[9];
  const float* bv = (const float*)d_in[10];
  const float* Wo = (const float*)d_in[11];
  const float* bo = (const float*)d_in[12];
  float* out = (float*)d_out;

  unsigned short* ws  = (unsigned short*)d_ws;
  unsigned short* Wt  = ws;                          // 4 * 768*768
  unsigned short* qhb = Wt + (size_t)4 * ND * ND;
  unsigned short* khb = qhb + (size_t)NM * ND;
  unsigned short* vhT = khb + (size_t)NM * ND;       // [(b*NH+h)*64+d][1024]
  unsigned short* aob = vhT + (size_t)NM * ND;

  wt_kernel<<<dim3(ND / 32, ND / 32, 4), 256, 0, stream>>>(Wq, Wk, Wv, Wo, Wt);

  // Q and K projections (fp32 A reg-staged, convert at ds_write)
  gemm_kernel<0><<<dim3(NM / 128, ND / 128, 2), 256, 0, stream>>>(
      q, k, nullptr, Wt, bq, bk, qhb, khb, nullptr);
  // V projection -> transposed vhT
  gemm_kernel<2><<<dim3(NM / 128, ND / 128), 256, 0, stream>>>(
      v, nullptr, nullptr, Wt, bv, nullptr, vhT, nullptr, nullptr);

  attn_kernel<<<dim3(NL / 128, NB * NH), 256, 0, stream>>>(qhb, khb, vhT, mask, aob);

  gemm_kernel<3><<<dim3(NM / 128, ND / 128), 256, 0, stream>>>(
      nullptr, nullptr, aob, Wt, bo, nullptr, nullptr, nullptr, out);
}